// Round 4
// baseline (5526.667 us; speedup 1.0000x reference)
//
#include <hip/hip_runtime.h>

// GNN node embedding (GINEConv x5), fp32, MI355X gfx950.
// N=50000 nodes, E=800000 edges, D=64, X_DIM=92, EA_DIM=50, L=5.
//
// R3 redesign: round-2 k_aggr was latency-bound (VALUBusy 13.5%, HBM 12%) --
// scalar-path streaming of ea + serial per-edge chains. Now all bulk loads go
// through the vector path: k_edge stages 128 CSR-ordered ea rows into LDS with
// coalesced float2 gathers, computes lane=d with uniform LDS broadcast reads,
// accumulates per-dst runs in registers, atomic-flushes at segment boundaries.
// Weights for atom/mlp kernels staged in LDS (W slices > 16KB scalar L1).

#define NN 50000
#define NE 800000
#define D 64
#define NL 5
#define XD 92
#define EAD 50
#define BN_EPS 1e-5f
#define NBLK ((NN + 255) / 256)   // 196 scan blocks
#define TILE_E 128                // edges per block in k_edge (NE = 6250*128)

// ---------------- prep: transpose weights ----------------
__global__ void k_prep(const float* __restrict__ atomW, const float* __restrict__ W1,
                       const float* __restrict__ W2, float* __restrict__ atomWt,
                       float* __restrict__ W1t, float* __restrict__ W2t) {
  int tid = blockIdx.x * blockDim.x + threadIdx.x;
  int nt = gridDim.x * blockDim.x;
  for (int i = tid; i < XD * D; i += nt) {
    int k = i / D, d = i % D;
    atomWt[d * XD + k] = atomW[i];
  }
  for (int i = tid; i < NL * D * D; i += nt) {
    int l = i / (D * D), r = i % (D * D);
    int k = r / D, d = r % D;
    W1t[(l * D + d) * D + k] = W1[i];
    W2t[(l * D + d) * D + k] = W2[i];
  }
}

// ---------------- atom encoder: h = x @ atom_W + b ----------------
// lane = node; x row in VGPRs; transposed W staged in LDS, rows read as
// uniform-address (broadcast) float4 ds_reads.
__global__ __launch_bounds__(256) void k_atom(const float* __restrict__ x,
    const float* __restrict__ Wt, const float* __restrict__ b,
    float* __restrict__ h) {
  __shared__ float sw[D * XD];  // 23552 B
  for (int i = threadIdx.x; i < D * XD; i += 256) sw[i] = Wt[i];
  __syncthreads();
  int n = blockIdx.x * blockDim.x + threadIdx.x;
  if (n >= NN) return;
  const float* xp = x + (size_t)n * XD;
  float xr[XD];
#pragma unroll
  for (int k = 0; k < XD; k += 4) {  // 368B rows, 16B-aligned
    float4 v = *reinterpret_cast<const float4*>(xp + k);
    xr[k] = v.x; xr[k + 1] = v.y; xr[k + 2] = v.z; xr[k + 3] = v.w;
  }
  float hr[D];
#pragma unroll
  for (int d = 0; d < D; ++d) {
    const float4* wr = reinterpret_cast<const float4*>(&sw[d * XD]);  // uniform
    float a0 = 0.f, a1 = 0.f, a2 = 0.f, a3 = 0.f;
#pragma unroll
    for (int q = 0; q < XD / 4; ++q) {
      float4 w = wr[q];
      a0 = fmaf(xr[4 * q + 0], w.x, a0);
      a1 = fmaf(xr[4 * q + 1], w.y, a1);
      a2 = fmaf(xr[4 * q + 2], w.z, a2);
      a3 = fmaf(xr[4 * q + 3], w.w, a3);
    }
    hr[d] = (a0 + a1) + (a2 + a3) + b[d];
  }
  float* hp = h + (size_t)n * D;
#pragma unroll
  for (int d = 0; d < D; d += 4)
    *reinterpret_cast<float4*>(hp + d) = make_float4(hr[d], hr[d+1], hr[d+2], hr[d+3]);
}

// ---------------- CSR build ----------------
__global__ __launch_bounds__(256) void k_deg(const int* __restrict__ ei,
                                             int* __restrict__ deg) {
  int e = blockIdx.x * blockDim.x + threadIdx.x;
  if (e < NE) atomicAdd(&deg[ei[NE + e]], 1);
}

__global__ __launch_bounds__(256) void k_scan_a(const int* __restrict__ deg,
    int* __restrict__ lps, int* __restrict__ bsum) {
  __shared__ int s[256];
  int t = threadIdx.x;
  int i = blockIdx.x * 256 + t;
  int v = (i < NN) ? deg[i] : 0;
  s[t] = v;
  __syncthreads();
#pragma unroll
  for (int off = 1; off < 256; off <<= 1) {
    int xv = (t >= off) ? s[t - off] : 0;
    __syncthreads();
    s[t] += xv;
    __syncthreads();
  }
  if (i < NN) lps[i] = s[t] - v;         // exclusive
  if (t == 255) bsum[blockIdx.x] = s[255];
}

__global__ __launch_bounds__(256) void k_scan_b(const int* __restrict__ bsum,
                                                int* __restrict__ bpre) {
  __shared__ int s[256];
  int t = threadIdx.x;
  int v = (t < NBLK) ? bsum[t] : 0;
  s[t] = v;
  __syncthreads();
#pragma unroll
  for (int off = 1; off < 256; off <<= 1) {
    int xv = (t >= off) ? s[t - off] : 0;
    __syncthreads();
    s[t] += xv;
    __syncthreads();
  }
  bpre[t] = s[t] - v;
}

__global__ __launch_bounds__(256) void k_fill(const int* __restrict__ lps,
    const int* __restrict__ bpre, int* __restrict__ rowptr,
    int* __restrict__ cursor) {
  int i = blockIdx.x * blockDim.x + threadIdx.x;
  if (i < NN) {
    int v = lps[i] + bpre[i >> 8];
    rowptr[i] = v;
    cursor[i] = v;
  }
  if (i == 0) rowptr[NN] = NE;
}

__global__ __launch_bounds__(256) void k_scatter(const int* __restrict__ ei,
    int* __restrict__ cursor, int* __restrict__ esrc, int* __restrict__ eidl,
    int* __restrict__ dstp) {
  int e = blockIdx.x * blockDim.x + threadIdx.x;
  if (e >= NE) return;
  int dst = ei[NE + e];
  int p = atomicAdd(&cursor[dst], 1);
  esrc[p] = ei[e];
  eidl[p] = e;
  dstp[p] = dst;
}

// ---------------- edge kernel: LDS-staged lin + run-length scatter ----------------
// Block = 256 threads / TILE_E=128 CSR-ordered edges. Stage: coalesced float2
// gathers of ea rows into LDS. Compute: wave w owns edges [w*32,(w+1)*32),
// lane = d; lin via 12x uniform ds_read_b128 + float2 tail; msg = relu(h[src]+lin+b);
// consecutive same-dst edges accumulate in a register, flush via unsafeAtomicAdd.
__global__ __launch_bounds__(256) void k_edge(const float* __restrict__ h,
    const float* __restrict__ ea, const float* __restrict__ eW,
    const float* __restrict__ eb, const int* __restrict__ esrc,
    const int* __restrict__ eidl, const int* __restrict__ dstp,
    int layer, float* __restrict__ agg) {
  __shared__ float2 sea2[TILE_E * 26];              // row stride 26 float2 = 208B
  __shared__ int s_src[TILE_E], s_dst[TILE_E], s_eid[TILE_E];
  int tid = threadIdx.x;
  int lane = tid & 63;
  int slot0 = blockIdx.x * TILE_E;

  const float* Wl = eW + (size_t)layer * EAD * D;
  float wc[EAD];
#pragma unroll
  for (int k = 0; k < EAD; ++k) wc[k] = Wl[k * D + lane];  // coalesced column
  float bd = eb[layer * D + lane];

  if (tid < TILE_E) {
    s_eid[tid] = eidl[slot0 + tid];
    s_src[tid] = esrc[slot0 + tid];
    s_dst[tid] = dstp[slot0 + tid];
  }
  __syncthreads();
  // stage ea rows: i -> (edge el, float2 k2); 25 consecutive threads share a row
  for (int i = tid; i < TILE_E * 25; i += 256) {
    int el = i / 25, k2 = i % 25;
    sea2[el * 26 + k2] =
        *reinterpret_cast<const float2*>(ea + (size_t)s_eid[el] * EAD + 2 * k2);
  }
  __syncthreads();

  int e0 = (tid >> 6) * 32;          // this wave's edge range
  int cur = s_dst[e0];
  float acc = 0.f;
#pragma unroll 2
  for (int j = 0; j < 32; ++j) {
    int el = e0 + j;
    int dst = s_dst[el];             // wave-uniform broadcast
    int src = s_src[el];
    if (dst != cur) {                // uniform branch
      unsafeAtomicAdd(&agg[(size_t)cur * D + lane], acc);
      acc = 0.f;
      cur = dst;
    }
    const float4* er = reinterpret_cast<const float4*>(&sea2[el * 26]);  // uniform
    float a0 = 0.f, a1 = 0.f, a2 = 0.f, a3 = 0.f;
#pragma unroll
    for (int q = 0; q < 12; ++q) {
      float4 v = er[q];
      a0 = fmaf(v.x, wc[4 * q + 0], a0);
      a1 = fmaf(v.y, wc[4 * q + 1], a1);
      a2 = fmaf(v.z, wc[4 * q + 2], a2);
      a3 = fmaf(v.w, wc[4 * q + 3], a3);
    }
    float2 tl = sea2[el * 26 + 24];
    a0 = fmaf(tl.x, wc[48], a0);
    a1 = fmaf(tl.y, wc[49], a1);
    float lin = (a0 + a1) + (a2 + a3) + bd;
    acc += fmaxf(h[(size_t)src * D + lane] + lin, 0.f);
  }
  unsafeAtomicAdd(&agg[(size_t)cur * D + lane], acc);
}

// ---------------- node MLP: t = relu(z@W1+b1)@W2+b2, z=(1+eps)h+agg ----------------
// t written in-place over agg (each thread reads its full row first).
__global__ __launch_bounds__(256) void k_mlp(const float* __restrict__ h,
    const float* __restrict__ W1t, const float* __restrict__ b1,
    const float* __restrict__ W2t, const float* __restrict__ b2,
    const float* __restrict__ eps, int layer, float* __restrict__ agg) {
  __shared__ float w1[D * D];  // 16 KB
  __shared__ float w2[D * D];  // 16 KB
  {
    const float* W1l = W1t + (size_t)layer * D * D;
    const float* W2l = W2t + (size_t)layer * D * D;
    for (int i = threadIdx.x; i < D * D; i += 256) {
      w1[i] = W1l[i];
      w2[i] = W2l[i];
    }
  }
  __syncthreads();
  int n = blockIdx.x * blockDim.x + threadIdx.x;
  if (n >= NN) return;
  float ope = 1.f + eps[layer];
  const float* hp = h + (size_t)n * D;
  float* ap = (float*)(agg + (size_t)n * D);
  float zr[D];
#pragma unroll
  for (int k = 0; k < D; k += 4) {
    float4 hv = *reinterpret_cast<const float4*>(hp + k);
    float4 av = *reinterpret_cast<const float4*>(ap + k);
    zr[k]   = fmaf(ope, hv.x, av.x);
    zr[k+1] = fmaf(ope, hv.y, av.y);
    zr[k+2] = fmaf(ope, hv.z, av.z);
    zr[k+3] = fmaf(ope, hv.w, av.w);
  }
  const float* b1l = b1 + layer * D;
  float y[D];
#pragma unroll
  for (int d = 0; d < D; ++d) {
    const float4* wr = reinterpret_cast<const float4*>(&w1[d * D]);  // uniform
    float a0 = 0.f, a1 = 0.f, a2 = 0.f, a3 = 0.f;
#pragma unroll
    for (int q = 0; q < D / 4; ++q) {
      float4 w = wr[q];
      a0 = fmaf(zr[4 * q + 0], w.x, a0);
      a1 = fmaf(zr[4 * q + 1], w.y, a1);
      a2 = fmaf(zr[4 * q + 2], w.z, a2);
      a3 = fmaf(zr[4 * q + 3], w.w, a3);
    }
    y[d] = fmaxf((a0 + a1) + (a2 + a3) + b1l[d], 0.f);
  }
  const float* b2l = b2 + layer * D;
#pragma unroll
  for (int d = 0; d < D; ++d) {
    const float4* wr = reinterpret_cast<const float4*>(&w2[d * D]);  // uniform
    float a0 = 0.f, a1 = 0.f, a2 = 0.f, a3 = 0.f;
#pragma unroll
    for (int q = 0; q < D / 4; ++q) {
      float4 w = wr[q];
      a0 = fmaf(y[4 * q + 0], w.x, a0);
      a1 = fmaf(y[4 * q + 1], w.y, a1);
      a2 = fmaf(y[4 * q + 2], w.z, a2);
      a3 = fmaf(y[4 * q + 3], w.w, a3);
    }
    zr[d] = (a0 + a1) + (a2 + a3) + b2l[d];
  }
#pragma unroll
  for (int d = 0; d < D; d += 4)
    *reinterpret_cast<float4*>(ap + d) = make_float4(zr[d], zr[d+1], zr[d+2], zr[d+3]);
}

// ---------------- BN stats: per-feature sum / sumsq ----------------
__global__ __launch_bounds__(256) void k_stats(const float* __restrict__ t,
                                               float* __restrict__ stats) {
  int lane = threadIdx.x & 63;
  int w = threadIdx.x >> 6;
  int gw = blockIdx.x * 4 + w;
  int nw = gridDim.x * 4;
  float s = 0.f, q = 0.f;
  for (int n = gw; n < NN; n += nw) {
    float v = t[(size_t)n * D + lane];
    s += v;
    q = fmaf(v, v, q);
  }
  __shared__ float ls[8][64];
  ls[w][lane] = s;
  ls[4 + w][lane] = q;
  __syncthreads();
  if (threadIdx.x < D) {
    float S = ls[0][lane] + ls[1][lane] + ls[2][lane] + ls[3][lane];
    float Q = ls[4][lane] + ls[5][lane] + ls[6][lane] + ls[7][lane];
    unsafeAtomicAdd(&stats[lane], S);
    unsafeAtomicAdd(&stats[D + lane], Q);
  }
}

// ---------------- BN apply (+relu except last layer) ----------------
__global__ __launch_bounds__(256) void k_apply(const float* __restrict__ t,
    const float* __restrict__ stats, const float* __restrict__ gamma,
    const float* __restrict__ beta, int layer, int last, float* __restrict__ o) {
  const float inv = 1.f / (float)NN;
  int i = blockIdx.x * blockDim.x + threadIdx.x;
  int nt = gridDim.x * blockDim.x;
  for (; i < NN * D / 4; i += nt) {
    int d0 = (i & 15) * 4;
    float4 v = reinterpret_cast<const float4*>(t)[i];
    float vv[4] = {v.x, v.y, v.z, v.w};
    float r[4];
#pragma unroll
    for (int c = 0; c < 4; ++c) {
      int d = d0 + c;
      float mu = stats[d] * inv;
      float var = fmaf(-mu, mu, stats[D + d] * inv);
      float sc = gamma[layer * D + d] / sqrtf(var + BN_EPS);
      float val = fmaf(vv[c] - mu, sc, beta[layer * D + d]);
      r[c] = last ? val : fmaxf(val, 0.f);
    }
    reinterpret_cast<float4*>(o)[i] = make_float4(r[0], r[1], r[2], r[3]);
  }
}

extern "C" void kernel_launch(void* const* d_in, const int* in_sizes, int n_in,
                              void* d_out, int out_size, void* d_ws, size_t ws_size,
                              hipStream_t stream) {
  const float* x     = (const float*)d_in[0];
  const int*   ei    = (const int*)d_in[1];
  const float* ea    = (const float*)d_in[2];
  const float* atomW = (const float*)d_in[3];
  const float* atomB = (const float*)d_in[4];
  const float* eW    = (const float*)d_in[5];
  const float* eb    = (const float*)d_in[6];
  const float* W1    = (const float*)d_in[7];
  const float* b1    = (const float*)d_in[8];
  const float* W2    = (const float*)d_in[9];
  const float* b2    = (const float*)d_in[10];
  const float* eps   = (const float*)d_in[11];
  const float* gamma = (const float*)d_in[12];
  const float* beta  = (const float*)d_in[13];
  float* out = (float*)d_out;

  char* ws = (char*)d_ws;
  float* h      = (float*)ws;                                // NN*D
  float* agg    = h + (size_t)NN * D;                        // NN*D (agg, then t)
  float* stats  = agg + (size_t)NN * D;                      // 2*D (adjacent to agg)
  float* atomWt = stats + 2 * D;                             // D*XD
  float* W1t    = atomWt + D * XD;                           // NL*D*D
  float* W2t    = W1t + NL * D * D;                          // NL*D*D
  int*   deg    = (int*)(W2t + NL * D * D);                  // NN
  int*   lps    = deg + NN;                                  // NN
  int*   rowptr = lps + NN;                                  // NN+1
  int*   cursor = rowptr + NN + 1;                           // NN
  int*   bsum   = cursor + NN;                               // 256
  int*   bpre   = bsum + 256;                                // 256
  int*   esrc   = bpre + 256;                                // NE
  int*   eidl   = esrc + NE;                                 // NE
  int*   dstp   = eidl + NE;                                 // NE
  // total ws use ~= 36.5 MB

  // weights + atom encoder
  k_prep<<<64, 256, 0, stream>>>(atomW, W1, W2, atomWt, W1t, W2t);
  k_atom<<<(NN + 255) / 256, 256, 0, stream>>>(x, atomWt, atomB, h);

  // CSR build (dst-sorted edge order)
  hipMemsetAsync(deg, 0, (size_t)NN * 4, stream);
  k_deg<<<(NE + 255) / 256, 256, 0, stream>>>(ei, deg);
  k_scan_a<<<NBLK, 256, 0, stream>>>(deg, lps, bsum);
  k_scan_b<<<1, 256, 0, stream>>>(bsum, bpre);
  k_fill<<<NBLK, 256, 0, stream>>>(lps, bpre, rowptr, cursor);
  k_scatter<<<(NE + 255) / 256, 256, 0, stream>>>(ei, cursor, esrc, eidl, dstp);

  for (int l = 0; l < NL; ++l) {
    hipMemsetAsync(agg, 0, ((size_t)NN * D + 2 * D) * 4, stream);  // agg + stats
    k_edge<<<NE / TILE_E, 256, 0, stream>>>(h, ea, eW, eb, esrc, eidl, dstp, l, agg);
    k_mlp<<<NBLK, 256, 0, stream>>>(h, W1t, b1, W2t, b2, eps, l, agg);
    k_stats<<<512, 256, 0, stream>>>(agg, stats);
    float* ho = (l == NL - 1) ? out : h;
    k_apply<<<1024, 256, 0, stream>>>(agg, stats, gamma, beta, l, (l == NL - 1) ? 1 : 0, ho);
  }
}

// Round 6
// 2220.984 us; speedup vs baseline: 2.4884x; 2.4884x over previous
//
#include <hip/hip_runtime.h>

// GNN node embedding (GINEConv x5), fp32, MI355X gfx950.
// N=50000 nodes, E=800000 edges, D=64, X_DIM=92, EA_DIM=50, L=5.
//
// R5 = R4 resubmission (R4 bench died on container infra, never measured).
// R4: k_mlp/k_atom reverted to R2 form (uniform global s_load weights ->
// SGPR-operand FMAs; LDS-broadcast version spilled: 256 VGPR, 1.4GB scratch
// traffic, 850us). k_edge redesigned lane=edge: per-lane ea row in VGPRs,
// s_load weights (transposed), per-wave LDS msg[64][33] transpose buffer,
// half-wave aggregation with run-length register accumulation + atomic flush.

#define NN 50000
#define NE 800000
#define D 64
#define NL 5
#define XD 92
#define EAD 50
#define BN_EPS 1e-5f
#define NBLK ((NN + 255) / 256)   // 196 scan blocks
#define TILE_E 256                // edges per block (64 per wave), NE = 3125*256

// ---------------- prep: transpose weights ----------------
__global__ void k_prep(const float* __restrict__ atomW, const float* __restrict__ W1,
                       const float* __restrict__ W2, const float* __restrict__ eW,
                       float* __restrict__ atomWt, float* __restrict__ W1t,
                       float* __restrict__ W2t, float* __restrict__ eWt) {
  int tid = blockIdx.x * blockDim.x + threadIdx.x;
  int nt = gridDim.x * blockDim.x;
  for (int i = tid; i < XD * D; i += nt) {
    int k = i / D, d = i % D;
    atomWt[d * XD + k] = atomW[i];
  }
  for (int i = tid; i < NL * D * D; i += nt) {
    int l = i / (D * D), r = i % (D * D);
    int k = r / D, d = r % D;
    W1t[(l * D + d) * D + k] = W1[i];
    W2t[(l * D + d) * D + k] = W2[i];
  }
  for (int i = tid; i < NL * EAD * D; i += nt) {
    int l = i / (EAD * D), r = i % (EAD * D);
    int k = r / D, d = r % D;
    eWt[(l * D + d) * EAD + k] = eW[i];
  }
}

// ---------------- atom encoder: h = x @ atom_W + b (R2 form) ----------------
// lane = node; x row in VGPRs; transposed-W rows are uniform global loads ->
// s_loads -> SGPR-operand v_fmac (no LDS, no spill).
__global__ __launch_bounds__(256) void k_atom(const float* __restrict__ x,
    const float* __restrict__ Wt, const float* __restrict__ b,
    float* __restrict__ h) {
  int n = blockIdx.x * blockDim.x + threadIdx.x;
  if (n >= NN) return;
  const float* xp = x + (size_t)n * XD;
  float xr[XD];
#pragma unroll
  for (int k = 0; k < XD; k += 4) {  // 368B rows, 16B-aligned
    float4 v = *reinterpret_cast<const float4*>(xp + k);
    xr[k] = v.x; xr[k + 1] = v.y; xr[k + 2] = v.z; xr[k + 3] = v.w;
  }
  float hr[D];
#pragma unroll
  for (int d = 0; d < D; ++d) {
    const float* wr = Wt + d * XD;  // uniform address -> s_loads
    float a0 = 0.f, a1 = 0.f, a2 = 0.f, a3 = 0.f;
#pragma unroll
    for (int k = 0; k < XD; k += 4) {
      a0 = fmaf(xr[k + 0], wr[k + 0], a0);
      a1 = fmaf(xr[k + 1], wr[k + 1], a1);
      a2 = fmaf(xr[k + 2], wr[k + 2], a2);
      a3 = fmaf(xr[k + 3], wr[k + 3], a3);
    }
    hr[d] = (a0 + a1) + (a2 + a3) + b[d];
  }
  float* hp = h + (size_t)n * D;
#pragma unroll
  for (int d = 0; d < D; d += 4)
    *reinterpret_cast<float4*>(hp + d) = make_float4(hr[d], hr[d+1], hr[d+2], hr[d+3]);
}

// ---------------- CSR build ----------------
__global__ __launch_bounds__(256) void k_deg(const int* __restrict__ ei,
                                             int* __restrict__ deg) {
  int e = blockIdx.x * blockDim.x + threadIdx.x;
  if (e < NE) atomicAdd(&deg[ei[NE + e]], 1);
}

__global__ __launch_bounds__(256) void k_scan_a(const int* __restrict__ deg,
    int* __restrict__ lps, int* __restrict__ bsum) {
  __shared__ int s[256];
  int t = threadIdx.x;
  int i = blockIdx.x * 256 + t;
  int v = (i < NN) ? deg[i] : 0;
  s[t] = v;
  __syncthreads();
#pragma unroll
  for (int off = 1; off < 256; off <<= 1) {
    int xv = (t >= off) ? s[t - off] : 0;
    __syncthreads();
    s[t] += xv;
    __syncthreads();
  }
  if (i < NN) lps[i] = s[t] - v;         // exclusive
  if (t == 255) bsum[blockIdx.x] = s[255];
}

__global__ __launch_bounds__(256) void k_scan_b(const int* __restrict__ bsum,
                                                int* __restrict__ bpre) {
  __shared__ int s[256];
  int t = threadIdx.x;
  int v = (t < NBLK) ? bsum[t] : 0;
  s[t] = v;
  __syncthreads();
#pragma unroll
  for (int off = 1; off < 256; off <<= 1) {
    int xv = (t >= off) ? s[t - off] : 0;
    __syncthreads();
    s[t] += xv;
    __syncthreads();
  }
  bpre[t] = s[t] - v;
}

__global__ __launch_bounds__(256) void k_fill(const int* __restrict__ lps,
    const int* __restrict__ bpre, int* __restrict__ rowptr,
    int* __restrict__ cursor) {
  int i = blockIdx.x * blockDim.x + threadIdx.x;
  if (i < NN) {
    int v = lps[i] + bpre[i >> 8];
    rowptr[i] = v;
    cursor[i] = v;
  }
  if (i == 0) rowptr[NN] = NE;
}

__global__ __launch_bounds__(256) void k_scatter(const int* __restrict__ ei,
    int* __restrict__ cursor, int* __restrict__ esrc, int* __restrict__ eidl,
    int* __restrict__ dstp) {
  int e = blockIdx.x * blockDim.x + threadIdx.x;
  if (e >= NE) return;
  int dst = ei[NE + e];
  int p = atomicAdd(&cursor[dst], 1);
  esrc[p] = ei[e];
  eidl[p] = e;
  dstp[p] = dst;
}

// ---------------- edge kernel: lane = edge ----------------
// Each wave owns 64 CSR-ordered edges. Per lane: own ea row in 13 float4 VGPRs.
// Chunked d (2 x 32): phase A computes lin[d] per lane with uniform s_load
// weights (transposed eWt), writes msg[edge][dc] to per-wave LDS (stride 33,
// conflict-free). Phase B: half-wave per edge (l31 = d), ds_read_b32 msg +
// 2 shfl + coalesced h row slice; run-length accumulate in a register, flush
// via unsafeAtomicAdd when dst changes. No cross-wave LDS sharing -> no
// __syncthreads; compiler orders within-wave LDS ops.
__global__ __launch_bounds__(256) void k_edge(const float* __restrict__ h,
    const float* __restrict__ ea, const float* __restrict__ eWt,
    const float* __restrict__ eb, const int* __restrict__ esrc,
    const int* __restrict__ eidl, const int* __restrict__ dstp,
    int layer, float* __restrict__ agg) {
  __shared__ float msg[4][64 * 33];  // 33.8 KB
  int tid = threadIdx.x;
  int lane = tid & 63;
  int w = tid >> 6;
  int slot = blockIdx.x * TILE_E + w * 64 + lane;

  int eid  = eidl[slot];   // original edge id (for ea row)
  int vsrc = esrc[slot];
  int vdst = dstp[slot];

  const float* ep = ea + (size_t)eid * EAD;
  float4 ear[13];
#pragma unroll
  for (int q = 0; q < 12; ++q)
    ear[q] = *reinterpret_cast<const float4*>(ep + 4 * q);
  {
    float2 t2 = *reinterpret_cast<const float2*>(ep + 48);
    ear[12] = make_float4(t2.x, t2.y, 0.f, 0.f);
  }

  const float* Wl = eWt + (size_t)layer * D * EAD;
  const float* bl = eb + (size_t)layer * D;
  float* mw = msg[w];
  int half = lane >> 5;
  int l31 = lane & 31;

#pragma unroll
  for (int c = 0; c < 2; ++c) {
    // ---- phase A: lin for d in [c*32, c*32+32), lane = edge ----
#pragma unroll 2
    for (int dc = 0; dc < 32; ++dc) {
      int d = c * 32 + dc;
      const float* wr = Wl + d * EAD;  // uniform -> s_loads (sL1-resident)
      float a0 = 0.f, a1 = 0.f, a2 = 0.f, a3 = 0.f;
#pragma unroll
      for (int q = 0; q < 12; ++q) {
        a0 = fmaf(ear[q].x, wr[4 * q + 0], a0);
        a1 = fmaf(ear[q].y, wr[4 * q + 1], a1);
        a2 = fmaf(ear[q].z, wr[4 * q + 2], a2);
        a3 = fmaf(ear[q].w, wr[4 * q + 3], a3);
      }
      a0 = fmaf(ear[12].x, wr[48], a0);
      a1 = fmaf(ear[12].y, wr[49], a1);
      mw[lane * 33 + dc] = (a0 + a1) + (a2 + a3) + bl[d];
    }
    // ---- phase B: half-wave per edge, l31 = d - c*32 ----
    float acc = 0.f;
    int cur = __shfl(vdst, half);
#pragma unroll 4
    for (int i = 0; i < 32; ++i) {
      int e = 2 * i + half;
      int dste = __shfl(vdst, e);
      int srce = __shfl(vsrc, e);
      if (dste != cur) {
        unsafeAtomicAdd(&agg[(size_t)cur * D + c * 32 + l31], acc);
        acc = 0.f;
        cur = dste;
      }
      float lin = mw[e * 33 + l31];
      float hv = h[(size_t)srce * D + c * 32 + l31];
      acc += fmaxf(hv + lin, 0.f);
    }
    unsafeAtomicAdd(&agg[(size_t)cur * D + c * 32 + l31], acc);
  }
}

// ---------------- node MLP (R2 form): t = relu(z@W1+b1)@W2+b2 ----------------
// z = (1+eps)h + agg; t written in-place over agg. Weights via uniform global
// s_loads (SGPR-operand FMAs) -- the no-spill structure.
__global__ __launch_bounds__(256) void k_mlp(const float* __restrict__ h,
    const float* __restrict__ W1t, const float* __restrict__ b1,
    const float* __restrict__ W2t, const float* __restrict__ b2,
    const float* __restrict__ eps, int layer, float* __restrict__ agg) {
  int n = blockIdx.x * blockDim.x + threadIdx.x;
  if (n >= NN) return;
  float ope = 1.f + eps[layer];
  const float* hp = h + (size_t)n * D;
  float* ap = agg + (size_t)n * D;
  float zr[D];
#pragma unroll
  for (int k = 0; k < D; k += 4) {
    float4 hv = *reinterpret_cast<const float4*>(hp + k);
    float4 av = *reinterpret_cast<const float4*>(ap + k);
    zr[k]   = fmaf(ope, hv.x, av.x);
    zr[k+1] = fmaf(ope, hv.y, av.y);
    zr[k+2] = fmaf(ope, hv.z, av.z);
    zr[k+3] = fmaf(ope, hv.w, av.w);
  }
  const float* W1l = W1t + (size_t)layer * D * D;
  const float* b1l = b1 + layer * D;
  float y[D];
#pragma unroll
  for (int d = 0; d < D; ++d) {
    const float* wr = W1l + d * D;  // uniform -> s_loads
    float a0 = 0.f, a1 = 0.f, a2 = 0.f, a3 = 0.f;
#pragma unroll
    for (int k = 0; k < D; k += 4) {
      a0 = fmaf(zr[k + 0], wr[k + 0], a0);
      a1 = fmaf(zr[k + 1], wr[k + 1], a1);
      a2 = fmaf(zr[k + 2], wr[k + 2], a2);
      a3 = fmaf(zr[k + 3], wr[k + 3], a3);
    }
    y[d] = fmaxf((a0 + a1) + (a2 + a3) + b1l[d], 0.f);
  }
  const float* W2l = W2t + (size_t)layer * D * D;
  const float* b2l = b2 + layer * D;
#pragma unroll
  for (int d = 0; d < D; ++d) {
    const float* wr = W2l + d * D;  // uniform -> s_loads
    float a0 = 0.f, a1 = 0.f, a2 = 0.f, a3 = 0.f;
#pragma unroll
    for (int k = 0; k < D; k += 4) {
      a0 = fmaf(y[k + 0], wr[k + 0], a0);
      a1 = fmaf(y[k + 1], wr[k + 1], a1);
      a2 = fmaf(y[k + 2], wr[k + 2], a2);
      a3 = fmaf(y[k + 3], wr[k + 3], a3);
    }
    zr[d] = (a0 + a1) + (a2 + a3) + b2l[d];
  }
#pragma unroll
  for (int d = 0; d < D; d += 4)
    *reinterpret_cast<float4*>(ap + d) = make_float4(zr[d], zr[d+1], zr[d+2], zr[d+3]);
}

// ---------------- BN stats: per-feature sum / sumsq ----------------
__global__ __launch_bounds__(256) void k_stats(const float* __restrict__ t,
                                               float* __restrict__ stats) {
  int lane = threadIdx.x & 63;
  int w = threadIdx.x >> 6;
  int gw = blockIdx.x * 4 + w;
  int nw = gridDim.x * 4;
  float s = 0.f, q = 0.f;
  for (int n = gw; n < NN; n += nw) {
    float v = t[(size_t)n * D + lane];
    s += v;
    q = fmaf(v, v, q);
  }
  __shared__ float ls[8][64];
  ls[w][lane] = s;
  ls[4 + w][lane] = q;
  __syncthreads();
  if (threadIdx.x < D) {
    float S = ls[0][lane] + ls[1][lane] + ls[2][lane] + ls[3][lane];
    float Q = ls[4][lane] + ls[5][lane] + ls[6][lane] + ls[7][lane];
    unsafeAtomicAdd(&stats[lane], S);
    unsafeAtomicAdd(&stats[D + lane], Q);
  }
}

// ---------------- BN apply (+relu except last layer) ----------------
__global__ __launch_bounds__(256) void k_apply(const float* __restrict__ t,
    const float* __restrict__ stats, const float* __restrict__ gamma,
    const float* __restrict__ beta, int layer, int last, float* __restrict__ o) {
  const float inv = 1.f / (float)NN;
  int i = blockIdx.x * blockDim.x + threadIdx.x;
  int nt = gridDim.x * blockDim.x;
  for (; i < NN * D / 4; i += nt) {
    int d0 = (i & 15) * 4;
    float4 v = reinterpret_cast<const float4*>(t)[i];
    float vv[4] = {v.x, v.y, v.z, v.w};
    float r[4];
#pragma unroll
    for (int c = 0; c < 4; ++c) {
      int d = d0 + c;
      float mu = stats[d] * inv;
      float var = fmaf(-mu, mu, stats[D + d] * inv);
      float sc = gamma[layer * D + d] / sqrtf(var + BN_EPS);
      float val = fmaf(vv[c] - mu, sc, beta[layer * D + d]);
      r[c] = last ? val : fmaxf(val, 0.f);
    }
    reinterpret_cast<float4*>(o)[i] = make_float4(r[0], r[1], r[2], r[3]);
  }
}

extern "C" void kernel_launch(void* const* d_in, const int* in_sizes, int n_in,
                              void* d_out, int out_size, void* d_ws, size_t ws_size,
                              hipStream_t stream) {
  const float* x     = (const float*)d_in[0];
  const int*   ei    = (const int*)d_in[1];
  const float* ea    = (const float*)d_in[2];
  const float* atomW = (const float*)d_in[3];
  const float* atomB = (const float*)d_in[4];
  const float* eW    = (const float*)d_in[5];
  const float* eb    = (const float*)d_in[6];
  const float* W1    = (const float*)d_in[7];
  const float* b1    = (const float*)d_in[8];
  const float* W2    = (const float*)d_in[9];
  const float* b2    = (const float*)d_in[10];
  const float* eps   = (const float*)d_in[11];
  const float* gamma = (const float*)d_in[12];
  const float* beta  = (const float*)d_in[13];
  float* out = (float*)d_out;

  char* ws = (char*)d_ws;
  float* h      = (float*)ws;                                // NN*D
  float* agg    = h + (size_t)NN * D;                        // NN*D (agg, then t)
  float* stats  = agg + (size_t)NN * D;                      // 2*D (adjacent to agg)
  float* atomWt = stats + 2 * D;                             // D*XD
  float* W1t    = atomWt + D * XD;                           // NL*D*D
  float* W2t    = W1t + NL * D * D;                          // NL*D*D
  float* eWt    = W2t + NL * D * D;                          // NL*D*EAD
  int*   deg    = (int*)(eWt + NL * D * EAD);                // NN
  int*   lps    = deg + NN;                                  // NN
  int*   rowptr = lps + NN;                                  // NN+1
  int*   cursor = rowptr + NN + 1;                           // NN
  int*   bsum   = cursor + NN;                               // 256
  int*   bpre   = bsum + 256;                                // 256
  int*   esrc   = bpre + 256;                                // NE
  int*   eidl   = esrc + NE;                                 // NE
  int*   dstp   = eidl + NE;                                 // NE
  // total ws use ~= 36.6 MB

  // weights + atom encoder
  k_prep<<<64, 256, 0, stream>>>(atomW, W1, W2, eW, atomWt, W1t, W2t, eWt);
  k_atom<<<(NN + 255) / 256, 256, 0, stream>>>(x, atomWt, atomB, h);

  // CSR build (dst-sorted edge order)
  hipMemsetAsync(deg, 0, (size_t)NN * 4, stream);
  k_deg<<<(NE + 255) / 256, 256, 0, stream>>>(ei, deg);
  k_scan_a<<<NBLK, 256, 0, stream>>>(deg, lps, bsum);
  k_scan_b<<<1, 256, 0, stream>>>(bsum, bpre);
  k_fill<<<NBLK, 256, 0, stream>>>(lps, bpre, rowptr, cursor);
  k_scatter<<<(NE + 255) / 256, 256, 0, stream>>>(ei, cursor, esrc, eidl, dstp);

  for (int l = 0; l < NL; ++l) {
    hipMemsetAsync(agg, 0, ((size_t)NN * D + 2 * D) * 4, stream);  // agg + stats
    k_edge<<<NE / TILE_E, 256, 0, stream>>>(h, ea, eWt, eb, esrc, eidl, dstp, l, agg);
    k_mlp<<<NBLK, 256, 0, stream>>>(h, W1t, b1, W2t, b2, eps, l, agg);
    k_stats<<<512, 256, 0, stream>>>(agg, stats);
    float* ho = (l == NL - 1) ? out : h;
    k_apply<<<1024, 256, 0, stream>>>(agg, stats, gamma, beta, l, (l == NL - 1) ? 1 : 0, ho);
  }
}